// Round 1
// 373.676 us; speedup vs baseline: 1.0091x; 1.0091x over previous
//
#include <hip/hip_runtime.h>
#include <hip/hip_bf16.h>
#include <math.h>

#define D_EMBED 512
#define NUM_HEADS 8
#define HEAD_DIM 64
#define D_FF 2048
#define BATCH 2
#define SEQ 4096
#define M_ROWS (BATCH*SEQ)   // 8192
// 0.125 * log2(e): folds softmax's exp->exp2 conversion into the Q projection
#define QSCALE 0.18033688011112042f

typedef __attribute__((ext_vector_type(8))) short short8;
typedef __attribute__((ext_vector_type(4))) short short4_t;
typedef __attribute__((ext_vector_type(4))) float f32x4;
typedef __attribute__((ext_vector_type(16))) float f32x16;

#if __has_builtin(__builtin_amdgcn_exp2f)
#define EXP2(x) __builtin_amdgcn_exp2f(x)
#else
#define EXP2(x) exp2f(x)
#endif

__device__ inline unsigned short f2b(float f) {
    union { float f; unsigned u; } v; v.f = f;
    unsigned r = v.u + 0x7fffu + ((v.u >> 16) & 1u);
    return (unsigned short)(r >> 16);
}

__device__ inline float b2f(short s) {
    union { unsigned u; float f; } v;
    v.u = ((unsigned)(unsigned short)s) << 16;
    return v.f;
}

// pack 4 fp32 -> 4 bf16 (RNE) via packed cvt
__device__ inline short4_t pk4(float p0, float p1, float p2, float p3) {
    union { __hip_bfloat162 h2[2]; short4_t s4; } u;
    u.h2[0] = __float22bfloat162_rn(make_float2(p0, p1));
    u.h2[1] = __float22bfloat162_rn(make_float2(p2, p3));
    return u.s4;
}

// pack 2 fp32 -> one dword of 2x bf16 (lo = first)
__device__ inline unsigned pk2(float lo, float hi) {
    union { __hip_bfloat162 h2; unsigned u; } x;
    x.h2 = __float22bfloat162_rn(make_float2(lo, hi));
    return x.u;
}

// permlane32_swap: r0 = {a.lo32lanes | b.lo32lanes->hi}, r1 = {a.hi32lanes->lo | b.hi32lanes}
__device__ inline void plswap(unsigned a, unsigned b, unsigned &r0, unsigned &r1) {
#if __has_builtin(__builtin_amdgcn_permlane32_swap)
    auto v = __builtin_amdgcn_permlane32_swap(a, b, false, false);
    r0 = (unsigned)v[0]; r1 = (unsigned)v[1];
#else
    unsigned ax = (unsigned)__shfl_xor((int)a, 32, 64);
    unsigned bx = (unsigned)__shfl_xor((int)b, 32, 64);
    bool hi = (threadIdx.x & 32) != 0;
    r0 = hi ? bx : a;
    r1 = hi ? b  : ax;
#endif
}

// build PV B-operand (P^T fragment) from 8 f32 p-values (keys split across lane halves)
__device__ inline short8 pfrag8(const float* p) {
    unsigned a0 = pk2(p[0], p[1]), a1 = pk2(p[2], p[3]);
    unsigned b0 = pk2(p[4], p[5]), b1 = pk2(p[6], p[7]);
    unsigned u0, u1, u2, u3;
    plswap(a0, b0, u0, u1);
    plswap(a1, b1, u2, u3);
    union { unsigned u[4]; short8 s; } r;
    r.u[0] = u0; r.u[1] = u2; r.u[2] = u1; r.u[3] = u3;
    return r.s;
}

__device__ inline void gl2lds16(const void* g, void* l) {
    __builtin_amdgcn_global_load_lds(
        (const __attribute__((address_space(1))) unsigned int*)g,
        (__attribute__((address_space(3))) unsigned int*)l, 16, 0, 0);
}

// ---------------------------------------------------------------------------
// GEMM 128x128: C[M][N] = A[M][K](bf16) * BT[N][K](bf16)^T + bias
// EPI 0: bf16; EPI 2: GELU->bf16.
// ---------------------------------------------------------------------------
template<int EPI>
__global__ __launch_bounds__(256) void gemm_bt(
    const unsigned short* __restrict__ A, const unsigned short* __restrict__ BT,
    const float* __restrict__ bias, void* __restrict__ Cout,
    int M, int N, int K)
{
    __shared__ __align__(16) unsigned short As[128*32];
    __shared__ __align__(16) unsigned short Bs[128*32];
    const int tid  = threadIdx.x;
    const int wave = tid >> 6, lane = tid & 63;
    const int wy = wave >> 1, wx = wave & 1;
    const int quad = lane >> 4, m16 = lane & 15;
    const int row0 = blockIdx.y * 128, n0 = blockIdx.x * 128;
    const int rdoff = (quad ^ ((m16 >> 1) & 3)) * 8;   // swizzled read chunk

    f32x4 acc[4][4];
#pragma unroll
    for (int i = 0; i < 4; i++)
#pragma unroll
        for (int j = 0; j < 4; j++) acc[i][j] = (f32x4){0.f,0.f,0.f,0.f};

    const int kIters = K >> 5;
    for (int kt = 0; kt < kIters; ++kt) {
        const int k0 = kt << 5;
#pragma unroll
        for (int it = 0; it < 2; ++it) {
            int g  = it*256 + tid;
            int r  = g >> 2;
            int c8 = (((g & 3) ^ ((g >> 3) & 3)) << 3);   // swizzled source chunk
            gl2lds16(A  + (size_t)(row0 + r)*K + k0 + c8, &As[(size_t)(it*256 + wave*64)*8]);
            gl2lds16(BT + (size_t)(n0  + r)*K + k0 + c8, &Bs[(size_t)(it*256 + wave*64)*8]);
        }
        __syncthreads();
        short8 a[4], b[4];
#pragma unroll
        for (int i = 0; i < 4; i++) a[i] = *(const short8*)&As[(wy*64 + i*16 + m16)*32 + rdoff];
#pragma unroll
        for (int j = 0; j < 4; j++) b[j] = *(const short8*)&Bs[(wx*64 + j*16 + m16)*32 + rdoff];
#pragma unroll
        for (int i = 0; i < 4; i++)
#pragma unroll
            for (int j = 0; j < 4; j++)
                acc[i][j] = __builtin_amdgcn_mfma_f32_16x16x32_bf16(a[i], b[j], acc[i][j], 0, 0, 0);
        __syncthreads();
    }

#pragma unroll
    for (int j = 0; j < 4; j++) {
        int col = n0 + wx*64 + j*16 + m16;
        float bj = bias[col];
#pragma unroll
        for (int i = 0; i < 4; i++) {
            int rbase = row0 + wy*64 + i*16 + quad*4;
#pragma unroll
            for (int r = 0; r < 4; r++) {
                float v = acc[i][j][r] + bj;
                size_t idx = (size_t)(rbase + r)*N + col;
                if (EPI == 0) {
                    ((unsigned short*)Cout)[idx] = f2b(v);
                } else {
                    float gv = 0.5f * v * (1.0f + erff(v * 0.70710678118654752f));
                    ((unsigned short*)Cout)[idx] = f2b(gv);
                }
            }
        }
    }
}

// ---------------------------------------------------------------------------
// QKV GEMM: epilogue scatters directly into Qp/Kp/Vt layouts.
// Qp,Kp: [bh][SEQ][64]; Vt: [bh][64 d][SEQ] (V transposed for 32x32 PV).
// Q region pre-scaled by QSCALE. Region (Q/K/V) is uniform per block.
// ---------------------------------------------------------------------------
__global__ __launch_bounds__(256) void gemm_qkv(
    const unsigned short* __restrict__ A, const unsigned short* __restrict__ BT,
    const float* __restrict__ bias,
    unsigned short* __restrict__ Qp, unsigned short* __restrict__ Kp,
    unsigned short* __restrict__ Vp)
{
    const int K = 512;
    __shared__ __align__(16) unsigned short As[128*32];
    __shared__ __align__(16) unsigned short Bs[128*32];
    const int tid  = threadIdx.x;
    const int wave = tid >> 6, lane = tid & 63;
    const int wy = wave >> 1, wx = wave & 1;
    const int quad = lane >> 4, m16 = lane & 15;
    const int row0 = blockIdx.y * 128, n0 = blockIdx.x * 128;
    const int rdoff = (quad ^ ((m16 >> 1) & 3)) * 8;
    const int region = n0 >> 9;   // 0=Q, 1=K, 2=V (uniform per block)

    f32x4 acc[4][4];
#pragma unroll
    for (int i = 0; i < 4; i++)
#pragma unroll
        for (int j = 0; j < 4; j++) acc[i][j] = (f32x4){0.f,0.f,0.f,0.f};

    for (int kt = 0; kt < 16; ++kt) {
        const int k0 = kt << 5;
#pragma unroll
        for (int it = 0; it < 2; ++it) {
            int g  = it*256 + tid;
            int r  = g >> 2;
            int c8 = (((g & 3) ^ ((g >> 3) & 3)) << 3);
            gl2lds16(A  + (size_t)(row0 + r)*K + k0 + c8, &As[(size_t)(it*256 + wave*64)*8]);
            gl2lds16(BT + (size_t)(n0  + r)*K + k0 + c8, &Bs[(size_t)(it*256 + wave*64)*8]);
        }
        __syncthreads();
        short8 a[4], b[4];
#pragma unroll
        for (int i = 0; i < 4; i++) a[i] = *(const short8*)&As[(wy*64 + i*16 + m16)*32 + rdoff];
#pragma unroll
        for (int j = 0; j < 4; j++) b[j] = *(const short8*)&Bs[(wx*64 + j*16 + m16)*32 + rdoff];
#pragma unroll
        for (int i = 0; i < 4; i++)
#pragma unroll
            for (int j = 0; j < 4; j++)
                acc[i][j] = __builtin_amdgcn_mfma_f32_16x16x32_bf16(a[i], b[j], acc[i][j], 0, 0, 0);
        __syncthreads();
    }

    const float sc = (region == 0) ? QSCALE : 1.0f;
#pragma unroll
    for (int j = 0; j < 4; j++) {
        int col = n0 + wx*64 + j*16 + m16;
        float bj = bias[col];
        int cc = col & 511, h = cc >> 6, d = cc & 63;
#pragma unroll
        for (int i = 0; i < 4; i++) {
            int rbase = row0 + wy*64 + i*16 + quad*4;
#pragma unroll
            for (int r = 0; r < 4; r++) {
                float v = (acc[i][j][r] + bj) * sc;
                int row = rbase + r;
                int b = row >> 12, l = row & 4095;
                size_t bh = (size_t)(b*8 + h);
                if (region == 0) {
                    Qp[(bh*SEQ + l)*64 + d] = f2b(v);
                } else if (region == 1) {
                    Kp[(bh*SEQ + l)*64 + d] = f2b(v);
                } else {
                    // V transposed: Vt[bh][d][l]
                    Vp[(bh*64 + d)*SEQ + l] = f2b(v);
                }
            }
        }
    }
}

// ---------------------------------------------------------------------------
// GEMM 64x128 tile (N=512 matmuls: grid 512 blocks). bf16 out.
// ---------------------------------------------------------------------------
__global__ __launch_bounds__(256) void gemm_bt64(
    const unsigned short* __restrict__ A, const unsigned short* __restrict__ BT,
    const float* __restrict__ bias, unsigned short* __restrict__ Cout,
    int M, int N, int K)
{
    __shared__ __align__(16) unsigned short As[64*32];
    __shared__ __align__(16) unsigned short Bs[128*32];
    const int tid  = threadIdx.x;
    const int wave = tid >> 6, lane = tid & 63;
    const int wy = wave >> 1, wx = wave & 1;
    const int quad = lane >> 4, m16 = lane & 15;
    const int row0 = blockIdx.y * 64, n0 = blockIdx.x * 128;
    const int rdoff = (quad ^ ((m16 >> 1) & 3)) * 8;

    f32x4 acc[2][4];
#pragma unroll
    for (int i = 0; i < 2; i++)
#pragma unroll
        for (int j = 0; j < 4; j++) acc[i][j] = (f32x4){0.f,0.f,0.f,0.f};

    const int kIters = K >> 5;
    for (int kt = 0; kt < kIters; ++kt) {
        const int k0 = kt << 5;
        {
            int r = tid >> 2;
            int c8 = (((tid & 3) ^ ((tid >> 3) & 3)) << 3);
            gl2lds16(A + (size_t)(row0 + r)*K + k0 + c8, &As[(size_t)(wave*64)*8]);
        }
#pragma unroll
        for (int it = 0; it < 2; ++it) {
            int g  = it*256 + tid;
            int r  = g >> 2;
            int c8 = (((g & 3) ^ ((g >> 3) & 3)) << 3);
            gl2lds16(BT + (size_t)(n0 + r)*K + k0 + c8, &Bs[(size_t)(it*256 + wave*64)*8]);
        }
        __syncthreads();
        short8 a[2], b[4];
#pragma unroll
        for (int i = 0; i < 2; i++) a[i] = *(const short8*)&As[(wy*32 + i*16 + m16)*32 + rdoff];
#pragma unroll
        for (int j = 0; j < 4; j++) b[j] = *(const short8*)&Bs[(wx*64 + j*16 + m16)*32 + rdoff];
#pragma unroll
        for (int i = 0; i < 2; i++)
#pragma unroll
            for (int j = 0; j < 4; j++)
                acc[i][j] = __builtin_amdgcn_mfma_f32_16x16x32_bf16(a[i], b[j], acc[i][j], 0, 0, 0);
        __syncthreads();
    }

#pragma unroll
    for (int j = 0; j < 4; j++) {
        int col = n0 + wx*64 + j*16 + m16;
        float bj = bias[col];
#pragma unroll
        for (int i = 0; i < 2; i++) {
            int rbase = row0 + wy*32 + i*16 + quad*4;
#pragma unroll
            for (int r = 0; r < 4; r++) {
                float v = acc[i][j][r] + bj;
                Cout[(size_t)(rbase + r)*N + col] = f2b(v);
            }
        }
    }
}

// ---------------------------------------------------------------------------
// prep: all 6 weight transposes + bias concat + mask flags + kmax zero in ONE
// kernel. Blocks 0..3071 = 32x32 transpose tiles; block 3072 = misc.
// ---------------------------------------------------------------------------
__global__ __launch_bounds__(256) void prep(
    const float* __restrict__ Wq, const float* __restrict__ Wk,
    const float* __restrict__ Wv, const float* __restrict__ Wo,
    const float* __restrict__ W1, const float* __restrict__ W2,
    const float* __restrict__ bq, const float* __restrict__ bk,
    const float* __restrict__ bv, const int* __restrict__ mask,
    unsigned short* __restrict__ WqkvT, unsigned short* __restrict__ WoT,
    unsigned short* __restrict__ W1T, unsigned short* __restrict__ W2T,
    float* __restrict__ bqkv, int* __restrict__ mflag, unsigned* __restrict__ kmax2)
{
    const int id = blockIdx.x, t = threadIdx.x;
    if (id == 3072) {
        if (t < 64) {   // mask flags (64 key-tiles of 128)
            const int* m = mask + t*128;
            int all = 1;
            for (int i = 0; i < 128; i += 4) {
                int4 v = *(const int4*)(m + i);
                all &= (v.x && v.y && v.z && v.w) ? 1 : 0;
            }
            mflag[t] = all;
        }
        if (t < 16) kmax2[t] = 0u;
        for (int i = t; i < 1536; i += 256)
            bqkv[i] = (i < 512) ? bq[i] : ((i < 1024) ? bk[i-512] : bv[i-1024]);
        return;
    }
    __shared__ float tt[32][33];
    const float* W; unsigned short* WT; int K, N, bx, by;
    if (id < 256)       { W = Wq; WT = WqkvT;            K = 512;  N = 512;  bx = id & 15;  by = id >> 4; }
    else if (id < 512)  { int l = id - 256;  W = Wk; WT = WqkvT + 512*512;  K = 512;  N = 512;  bx = l & 15; by = l >> 4; }
    else if (id < 768)  { int l = id - 512;  W = Wv; WT = WqkvT + 1024*512; K = 512;  N = 512;  bx = l & 15; by = l >> 4; }
    else if (id < 1024) { int l = id - 768;  W = Wo; WT = WoT;              K = 512;  N = 512;  bx = l & 15; by = l >> 4; }
    else if (id < 2048) { int l = id - 1024; W = W1; WT = W1T;              K = 512;  N = 2048; bx = l & 63; by = l >> 6; }
    else                { int l = id - 2048; W = W2; WT = W2T;              K = 2048; N = 512;  bx = l & 15; by = l >> 4; }
    const int n0 = bx*32, k0 = by*32;
    const int x = t & 31, y = t >> 5;
#pragma unroll
    for (int yy = y; yy < 32; yy += 8) tt[yy][x] = W[(size_t)(k0+yy)*N + n0 + x];
    __syncthreads();
#pragma unroll
    for (int yy = y; yy < 32; yy += 8) WT[(size_t)(n0+yy)*K + k0 + x] = f2b(tt[x][yy]);
}

// kmax2[bh] = max_row ||K_row||^2, via atomicMax on positive-float bits.
__global__ __launch_bounds__(256) void kmax_k(
    const unsigned short* __restrict__ Kp, unsigned* __restrict__ kmax2)
{
    const int bh = blockIdx.x, t = threadIdx.x;
    const int row = blockIdx.y*256 + t;
    const unsigned short* kp = Kp + ((size_t)bh*SEQ + row)*64;
    float s = 0.f;
#pragma unroll
    for (int c = 0; c < 8; ++c) {
        short8 v = *(const short8*)(kp + c*8);
#pragma unroll
        for (int j = 0; j < 8; ++j) { float f = b2f(v[j]); s += f*f; }
    }
#pragma unroll
    for (int off = 32; off >= 1; off >>= 1)
        s = fmaxf(s, __shfl_xor(s, off, 64));
    if ((t & 63) == 0) atomicMax(&kmax2[bh], __float_as_uint(s));
}

// ---------------------------------------------------------------------------
// Flash attention, 32x32x16 MFMA, fixed-bound softmax.
// grid (SEQ/256, B*H), 256 threads = 4 waves, 64 q-rows per wave (2 subtiles
// of 32). K tile [128][64] and V^T tile [64][128] double-buffered in LDS
// (64 KB), XOR-swizzled; one barrier per K/V tile (stage-next || compute).
// QK^T acc preloaded with -M so p = exp2(acc) directly. P (f32, 16 regs,
// keys split across lane halves) -> bf16 B-operand via cvt_pk +
// permlane32_swap; PV runs on the same full-rate 32x32x16 instruction.
// ---------------------------------------------------------------------------
__global__ __launch_bounds__(256, 1) void flash_attn(
    const unsigned short* __restrict__ Qp, const unsigned short* __restrict__ Kp,
    const unsigned short* __restrict__ Vt, const int* __restrict__ mask,
    const int* __restrict__ flags, const unsigned* __restrict__ kmax2,
    unsigned short* __restrict__ O)
{
    __shared__ __align__(16) unsigned short Ks[2][128*64];   // [buf][key][d]
    __shared__ __align__(16) unsigned short Vs[2][64*128];   // [buf][d][key]
    const int tid = threadIdx.x, wave = tid >> 6, lane = tid & 63;
    const int c = lane & 31, l5 = lane >> 5;
    const int bh = blockIdx.y, b = bh >> 3, h = bh & 7;
    const int qbase = blockIdx.x * 256 + wave * 64;

    const unsigned short* Qb = Qp + (size_t)bh*SEQ*64;
    const unsigned short* Kb = Kp + (size_t)bh*SEQ*64;
    const unsigned short* Vb = Vt + (size_t)bh*64*SEQ;
    const int* mbase = mask + b*SEQ;
    const int* fbase = flags + b*(SEQ/128);
    const float kmx = __uint_as_float(kmax2[bh]);

    // Q fragments: qf[qs][t] = Q[qbase+qs*32+c][t*16 + l5*8 .. +7]  (B-operand)
    short8 qf[2][4];
    float Mq[2];
#pragma unroll
    for (int qs = 0; qs < 2; ++qs) {
        const unsigned short* qp = Qb + (size_t)(qbase + qs*32 + c)*64 + l5*8;
        float qn2 = 0.f;
#pragma unroll
        for (int t = 0; t < 4; ++t) {
            qf[qs][t] = *(const short8*)(qp + t*16);
#pragma unroll
            for (int j = 0; j < 8; ++j) { float f = b2f(qf[qs][t][j]); qn2 += f*f; }
        }
        qn2 += __shfl_xor(qn2, 32, 64);      // halves hold complementary d
        Mq[qs] = sqrtf(qn2 * kmx);
    }

    f32x16 accO[2][2];                        // [qs][dgrp]: O^T[d][q]
#pragma unroll
    for (int qs = 0; qs < 2; ++qs)
#pragma unroll
        for (int dg = 0; dg < 2; ++dg)
#pragma unroll
            for (int r = 0; r < 16; ++r) accO[qs][dg][r] = 0.f;
    float rs0 = 0.f, rs1 = 0.f;

    // stage K[128][64] (8 chunks/row, swz ^row&7) and V^T[64][128]
    // (16 chunks/row, swz ^row&15) into buffer nb for key-tile ktn.
#define STAGE(nb, ktn) do {                                                   \
        const int key0s = (ktn)*128;                                          \
        _Pragma("unroll")                                                     \
        for (int it = 0; it < 4; ++it) {                                      \
            int idx = it*256 + tid;                                           \
            int r = idx >> 3, chn = idx & 7;                                  \
            gl2lds16(Kb + (size_t)(key0s + r)*64 + ((chn ^ (r & 7)) << 3),    \
                     &Ks[nb][(it*256 + wave*64)*8]);                          \
        }                                                                     \
        _Pragma("unroll")                                                     \
        for (int it = 0; it < 4; ++it) {                                      \
            int idx = it*256 + tid;                                           \
            int r = idx >> 4, chn = idx & 15;                                 \
            gl2lds16(Vb + (size_t)r*SEQ + key0s + ((chn ^ (r & 15)) << 3),    \
                     &Vs[nb][(it*256 + wave*64)*8]);                          \
        }                                                                     \
    } while (0)

    STAGE(0, 0);
    __syncthreads();                          // implicit vmcnt(0) drain
    int cb = 0;

    for (int kt = 0; kt < SEQ/128; ++kt) {
        if (kt + 1 < SEQ/128) STAGE(cb ^ 1, kt + 1);   // prefetch next tile
        const int allones = fbase[kt];
        const int key0 = kt * 128;
        const unsigned short* Kt  = Ks[cb];
        const unsigned short* Vtl = Vs[cb];

#pragma unroll
        for (int kg = 0; kg < 4; ++kg) {
            // ---- QK^T: A = K rows (32 keys), B = Q^T. acc preloaded -M.
            short8 kf[4];
#pragma unroll
            for (int t = 0; t < 4; ++t) {
                int row = kg*32 + c;
                int chn = (t*2 + l5) ^ (row & 7);
                kf[t] = *(const short8*)&Kt[row*64 + chn*8];
            }
            f32x16 s0, s1;
#pragma unroll
            for (int r = 0; r < 16; ++r) { s0[r] = -Mq[0]; s1[r] = -Mq[1]; }
#pragma unroll
            for (int t = 0; t < 4; ++t) {
                s0 = __builtin_amdgcn_mfma_f32_32x32x16_bf16(kf[t], qf[0][t], s0, 0, 0, 0);
                s1 = __builtin_amdgcn_mfma_f32_32x32x16_bf16(kf[t], qf[1][t], s1, 0, 0, 0);
            }
            if (!allones) {
#pragma unroll
                for (int r = 0; r < 16; ++r) {
                    int mv = mbase[key0 + kg*32 + (r & 3) + 8*(r >> 2) + 4*l5];
                    if (!mv) { s0[r] = -1e9f; s1[r] = -1e9f; }
                }
            }
            // ---- softmax numerators (keys for this lane: (r&3)+8*(r>>2)+4*l5)
            float pa[16], pc[16];
#pragma unroll
            for (int r = 0; r < 16; ++r) { pa[r] = EXP2(s0[r]); pc[r] = EXP2(s1[r]); }
            rs0 += (((pa[0]+pa[1])+(pa[2]+pa[3])) + ((pa[4]+pa[5])+(pa[6]+pa[7])))
                 + (((pa[8]+pa[9])+(pa[10]+pa[11])) + ((pa[12]+pa[13])+(pa[14]+pa[15])));
            rs1 += (((pc[0]+pc[1])+(pc[2]+pc[3])) + ((pc[4]+pc[5])+(pc[6]+pc[7])))
                 + (((pc[8]+pc[9])+(pc[10]+pc[11])) + ((pc[12]+pc[13])+(pc[14]+pc[15])));

            // ---- PV: A = V^T rows (32 d), B = P^T via cvt_pk + permlane32_swap
            short8 vf[2][2];   // [kchunk16][dgrp]
#pragma unroll
            for (int c2 = 0; c2 < 2; ++c2)
#pragma unroll
                for (int dg = 0; dg < 2; ++dg) {
                    int row = dg*32 + c;
                    int chn = ((kg*2 + c2)*2 + l5) ^ (row & 15);
                    vf[c2][dg] = *(const short8*)&Vtl[row*128 + chn*8];
                }
#pragma unroll
            for (int c2 = 0; c2 < 2; ++c2) {
                short8 pf0 = pfrag8(&pa[c2*8]);
                short8 pf1 = pfrag8(&pc[c2*8]);
                accO[0][0] = __builtin_amdgcn_mfma_f32_32x32x16_bf16(vf[c2][0], pf0, accO[0][0], 0, 0, 0);
                accO[0][1] = __builtin_amdgcn_mfma_f32_32x32x16_bf16(vf[c2][1], pf0, accO[0][1], 0, 0, 0);
                accO[1][0] = __builtin_amdgcn_mfma_f32_32x32x16_bf16(vf[c2][0], pf1, accO[1][0], 0, 0, 0);
                accO[1][1] = __builtin_amdgcn_mfma_f32_32x32x16_bf16(vf[c2][1], pf1, accO[1][1], 0, 0, 0);
            }
        }
        __syncthreads();      // drains prefetch vmcnt + protects buffer swap
        cb ^= 1;
    }
#undef STAGE

    // final l reduction (keys split across lane halves)
    rs0 += __shfl_xor(rs0, 32, 64);
    rs1 += __shfl_xor(rs1, 32, 64);
    float rl[2] = { 1.0f/rs0, 1.0f/rs1 };
#pragma unroll
    for (int qs = 0; qs < 2; ++qs) {
        int qrow = qbase + qs*32 + c;
        unsigned short* op = O + (size_t)(b*SEQ + qrow)*D_EMBED + h*HEAD_DIM;
#pragma unroll
        for (int dg = 0; dg < 2; ++dg)
#pragma unroll
            for (int q4 = 0; q4 < 4; ++q4) {
                short4_t o = pk4(accO[qs][dg][q4*4+0]*rl[qs], accO[qs][dg][q4*4+1]*rl[qs],
                                 accO[qs][dg][q4*4+2]*rl[qs], accO[qs][dg][q4*4+3]*rl[qs]);
                *(short4_t*)&op[dg*32 + q4*8 + l5*4] = o;
            }
    }
}

// ---------------------------------------------------------------------------
// ln1: y = LayerNorm(x_f32 + attn_bf16)*g + be -> bf16 only
// ---------------------------------------------------------------------------
__global__ __launch_bounds__(256) void ln_res1(
    const float* __restrict__ A, const unsigned short* __restrict__ Bv,
    const float* __restrict__ g, const float* __restrict__ be,
    unsigned short* __restrict__ Yb)
{
    const int wave = threadIdx.x >> 6, lane = threadIdx.x & 63;
    const int row = blockIdx.x * 4 + wave;
    const float* ap = A + (size_t)row*512 + lane*8;
    short8 bv = *(const short8*)(Bv + (size_t)row*512 + lane*8);
    float v[8]; float s = 0.f;
#pragma unroll
    for (int j = 0; j < 8; j++) { v[j] = ap[j] + b2f(bv[j]); s += v[j]; }
#pragma unroll
    for (int off = 32; off >= 1; off >>= 1) s += __shfl_xor(s, off, 64);
    float mu = s * (1.f/512.f);
    float q = 0.f;
#pragma unroll
    for (int j = 0; j < 8; j++) { v[j] -= mu; q += v[j]*v[j]; }
#pragma unroll
    for (int off = 32; off >= 1; off >>= 1) q += __shfl_xor(q, off, 64);
    float rstd = rsqrtf(q * (1.f/512.f) + 1e-5f);
#pragma unroll
    for (int j = 0; j < 8; j++) {
        float y = v[j]*rstd*g[lane*8+j] + be[lane*8+j];
        Yb[(size_t)row*512 + lane*8 + j] = f2b(y);
    }
}

// ---------------------------------------------------------------------------
// ln2: y = LayerNorm(h_bf16 + ff_bf16)*g + be -> fp32 out
// ---------------------------------------------------------------------------
__global__ __launch_bounds__(256) void ln_res2(
    const unsigned short* __restrict__ A, const unsigned short* __restrict__ Bv,
    const float* __restrict__ g, const float* __restrict__ be,
    float* __restrict__ Yf)
{
    const int wave = threadIdx.x >> 6, lane = threadIdx.x & 63;
    const int row = blockIdx.x * 4 + wave;
    short8 av = *(const short8*)(A  + (size_t)row*512 + lane*8);
    short8 bv = *(const short8*)(Bv + (size_t)row*512 + lane*8);
    float v[8]; float s = 0.f;
#pragma unroll
    for (int j = 0; j < 8; j++) { v[j] = b2f(av[j]) + b2f(bv[j]); s += v[j]; }
#pragma unroll
    for (int off = 32; off >= 1; off >>= 1) s += __shfl_xor(s, off, 64);
    float mu = s * (1.f/512.f);
    float q = 0.f;
#pragma unroll
    for (int j = 0; j < 8; j++) { v[j] -= mu; q += v[j]*v[j]; }
#pragma unroll
    for (int off = 32; off >= 1; off >>= 1) q += __shfl_xor(q, off, 64);
    float rstd = rsqrtf(q * (1.f/512.f) + 1e-5f);
#pragma unroll
    for (int j = 0; j < 8; j++) {
        float y = v[j]*rstd*g[lane*8+j] + be[lane*8+j];
        Yf[(size_t)row*512 + lane*8 + j] = y;
    }
}

__global__ __launch_bounds__(256) void cvt_f32_bf16(
    const float* __restrict__ X, unsigned short* __restrict__ Y, int n)
{
    int idx = (blockIdx.x * 256 + threadIdx.x) * 4;
    if (idx < n) {
        float4 v = *(const float4*)(X + idx);
        Y[idx+0] = f2b(v.x); Y[idx+1] = f2b(v.y);
        Y[idx+2] = f2b(v.z); Y[idx+3] = f2b(v.w);
    }
}

extern "C" void kernel_launch(void* const* d_in, const int* in_sizes, int n_in,
                              void* d_out, int out_size, void* d_ws, size_t ws_size,
                              hipStream_t stream)
{
    const float* x    = (const float*)d_in[0];
    const int*   mask = (const int*)  d_in[1];
    const float* Wq = (const float*)d_in[2];  const float* bq = (const float*)d_in[3];
    const float* Wk = (const float*)d_in[4];  const float* bk = (const float*)d_in[5];
    const float* Wv = (const float*)d_in[6];  const float* bv = (const float*)d_in[7];
    const float* Wo = (const float*)d_in[8];  const float* bo = (const float*)d_in[9];
    const float* ln1g = (const float*)d_in[10]; const float* ln1b = (const float*)d_in[11];
    const float* ln2g = (const float*)d_in[12]; const float* ln2b = (const float*)d_in[13];
    const float* W1 = (const float*)d_in[14]; const float* b1 = (const float*)d_in[15];
    const float* W2 = (const float*)d_in[16]; const float* b2 = (const float*)d_in[17];
    float* out = (float*)d_out;

    char* ws = (char*)d_ws;
    const size_t MB = 1024*1024;
    // liveness-planned map (peak 55 MB):
    unsigned short* xb    = (unsigned short*)(ws + 0);           // 0..8, dead after QKV GEMM
    unsigned short* WqkvT = (unsigned short*)(ws + 8*MB);        // 8..9.5
    unsigned short* W1T   = (unsigned short*)(ws + 10*MB);       // 10..12
    unsigned short* W2T   = (unsigned short*)(ws + 12*MB);       // 12..14
    unsigned short* WoT   = (unsigned short*)(ws + 14*MB);       // 14..14.5
    float*          bqkv  = (float*)(ws + 14*MB + 512*1024);     // 6 KB
    int*            mflag = (int*)(ws + 14*MB + 768*1024);       // 256 B
    unsigned*       kmaxb = (unsigned*)(ws + 14*MB + 772*1024);  // 64 B
    unsigned short* Qp    = (unsigned short*)(ws + 15*MB);       // 15..23, dead after flash
    unsigned short* Kp    = (unsigned short*)(ws + 23*MB);       // 23..31, dead after flash
    unsigned short* Vp    = (unsigned short*)(ws + 31*MB);       // 31..39 (V^T), dead after flash
    unsigned short* ctx   = (unsigned short*)(ws + 39*MB);       // 39..47, dead after Wo GEMM
    unsigned short* atfb  = (unsigned short*)(ws + 47*MB);       // 47..55, dead after ln1
    unsigned short* hb    = (unsigned short*)(ws + 0);           // 0..8, overlays dead xb
    unsigned short* Gb    = (unsigned short*)(ws + 15*MB);       // 15..47, overlays Qp/Kp/Vp/ctx
    unsigned short* ffb   = (unsigned short*)(ws + 47*MB);       // 47..55, overlays dead atfb

    cvt_f32_bf16<<<4096, 256, 0, stream>>>(x, xb, M_ROWS*D_EMBED);
    prep<<<3073, 256, 0, stream>>>(Wq, Wk, Wv, Wo, W1, W2, bq, bk, bv, mask,
                                   WqkvT, WoT, W1T, W2T, bqkv, mflag, kmaxb);

    // fused QKV projection -> direct Qp/Kp/Vt layouts (Q pre-scaled by QSCALE)
    gemm_qkv<<<dim3(12,64), 256, 0, stream>>>(xb, WqkvT, bqkv, Qp, Kp, Vp);

    kmax_k<<<dim3(16,16), 256, 0, stream>>>(Kp, kmaxb);
    flash_attn<<<dim3(SEQ/256, 16), 256, 0, stream>>>(Qp, Kp, Vp, mask, mflag, kmaxb, ctx);

    gemm_bt64<<<dim3(4,128), 256, 0, stream>>>(ctx, WoT, bo, atfb, M_ROWS, 512, 512);
    ln_res1<<<M_ROWS/4, 256, 0, stream>>>(x, atfb, ln1g, ln1b, hb);

    gemm_bt<2><<<dim3(16,64), 256, 0, stream>>>(hb, W1T, b1, Gb, M_ROWS, D_FF, 512);
    gemm_bt64<<<dim3(4,128), 256, 0, stream>>>(Gb, W2T, b2, ffb, M_ROWS, 512, D_FF);
    ln_res2<<<M_ROWS/4, 256, 0, stream>>>(hb, ffb, ln2g, ln2b, out);
}

// Round 2
// 346.139 us; speedup vs baseline: 1.0894x; 1.0796x over previous
//
#include <hip/hip_runtime.h>
#include <hip/hip_bf16.h>
#include <math.h>

#define D_EMBED 512
#define NUM_HEADS 8
#define HEAD_DIM 64
#define D_FF 2048
#define BATCH 2
#define SEQ 4096
#define M_ROWS (BATCH*SEQ)   // 8192
// 0.125 * log2(e): folds softmax's exp->exp2 conversion into the Q projection
#define QSCALE 0.18033688011112042f

typedef __attribute__((ext_vector_type(8))) short short8;
typedef __attribute__((ext_vector_type(4))) short short4_t;
typedef __attribute__((ext_vector_type(4))) float f32x4;
typedef __attribute__((ext_vector_type(16))) float f32x16;

#if __has_builtin(__builtin_amdgcn_exp2f)
#define EXP2(x) __builtin_amdgcn_exp2f(x)
#else
#define EXP2(x) exp2f(x)
#endif

__device__ inline unsigned short f2b(float f) {
    union { float f; unsigned u; } v; v.f = f;
    unsigned r = v.u + 0x7fffu + ((v.u >> 16) & 1u);
    return (unsigned short)(r >> 16);
}

__device__ inline float b2f(short s) {
    union { unsigned u; float f; } v;
    v.u = ((unsigned)(unsigned short)s) << 16;
    return v.f;
}

// pack 4 fp32 -> 4 bf16 (RNE) via packed cvt
__device__ inline short4_t pk4(float p0, float p1, float p2, float p3) {
    union { __hip_bfloat162 h2[2]; short4_t s4; } u;
    u.h2[0] = __float22bfloat162_rn(make_float2(p0, p1));
    u.h2[1] = __float22bfloat162_rn(make_float2(p2, p3));
    return u.s4;
}

// pack 2 fp32 -> one dword of 2x bf16 (lo = first)
__device__ inline unsigned pk2(float lo, float hi) {
    union { __hip_bfloat162 h2; unsigned u; } x;
    x.h2 = __float22bfloat162_rn(make_float2(lo, hi));
    return x.u;
}

// permlane32_swap: r0 = {a.lo32lanes | b.lo32lanes->hi}, r1 = {a.hi32lanes->lo | b.hi32lanes}
__device__ inline void plswap(unsigned a, unsigned b, unsigned &r0, unsigned &r1) {
#if __has_builtin(__builtin_amdgcn_permlane32_swap)
    auto v = __builtin_amdgcn_permlane32_swap(a, b, false, false);
    r0 = (unsigned)v[0]; r1 = (unsigned)v[1];
#else
    unsigned ax = (unsigned)__shfl_xor((int)a, 32, 64);
    unsigned bx = (unsigned)__shfl_xor((int)b, 32, 64);
    bool hi = (threadIdx.x & 32) != 0;
    r0 = hi ? bx : a;
    r1 = hi ? b  : ax;
#endif
}

// build PV B-operand (P^T fragment) from 8 f32 p-values (keys split across lane halves)
__device__ inline short8 pfrag8(const float* p) {
    unsigned a0 = pk2(p[0], p[1]), a1 = pk2(p[2], p[3]);
    unsigned b0 = pk2(p[4], p[5]), b1 = pk2(p[6], p[7]);
    unsigned u0, u1, u2, u3;
    plswap(a0, b0, u0, u1);
    plswap(a1, b1, u2, u3);
    union { unsigned u[4]; short8 s; } r;
    r.u[0] = u0; r.u[1] = u2; r.u[2] = u1; r.u[3] = u3;
    return r.s;
}

__device__ inline void gl2lds16(const void* g, void* l) {
    __builtin_amdgcn_global_load_lds(
        (const __attribute__((address_space(1))) unsigned int*)g,
        (__attribute__((address_space(3))) unsigned int*)l, 16, 0, 0);
}

// ---------------------------------------------------------------------------
// GEMM 128x128: C[M][N] = A[M][K](bf16) * BT[N][K](bf16)^T + bias
// EPI 0: bf16; EPI 2: GELU->bf16.
// ---------------------------------------------------------------------------
template<int EPI>
__global__ __launch_bounds__(256) void gemm_bt(
    const unsigned short* __restrict__ A, const unsigned short* __restrict__ BT,
    const float* __restrict__ bias, void* __restrict__ Cout,
    int M, int N, int K)
{
    __shared__ __align__(16) unsigned short As[128*32];
    __shared__ __align__(16) unsigned short Bs[128*32];
    const int tid  = threadIdx.x;
    const int wave = tid >> 6, lane = tid & 63;
    const int wy = wave >> 1, wx = wave & 1;
    const int quad = lane >> 4, m16 = lane & 15;
    const int row0 = blockIdx.y * 128, n0 = blockIdx.x * 128;
    const int rdoff = (quad ^ ((m16 >> 1) & 3)) * 8;   // swizzled read chunk

    f32x4 acc[4][4];
#pragma unroll
    for (int i = 0; i < 4; i++)
#pragma unroll
        for (int j = 0; j < 4; j++) acc[i][j] = (f32x4){0.f,0.f,0.f,0.f};

    const int kIters = K >> 5;
    for (int kt = 0; kt < kIters; ++kt) {
        const int k0 = kt << 5;
#pragma unroll
        for (int it = 0; it < 2; ++it) {
            int g  = it*256 + tid;
            int r  = g >> 2;
            int c8 = (((g & 3) ^ ((g >> 3) & 3)) << 3);   // swizzled source chunk
            gl2lds16(A  + (size_t)(row0 + r)*K + k0 + c8, &As[(size_t)(it*256 + wave*64)*8]);
            gl2lds16(BT + (size_t)(n0  + r)*K + k0 + c8, &Bs[(size_t)(it*256 + wave*64)*8]);
        }
        __syncthreads();
        short8 a[4], b[4];
#pragma unroll
        for (int i = 0; i < 4; i++) a[i] = *(const short8*)&As[(wy*64 + i*16 + m16)*32 + rdoff];
#pragma unroll
        for (int j = 0; j < 4; j++) b[j] = *(const short8*)&Bs[(wx*64 + j*16 + m16)*32 + rdoff];
#pragma unroll
        for (int i = 0; i < 4; i++)
#pragma unroll
            for (int j = 0; j < 4; j++)
                acc[i][j] = __builtin_amdgcn_mfma_f32_16x16x32_bf16(a[i], b[j], acc[i][j], 0, 0, 0);
        __syncthreads();
    }

#pragma unroll
    for (int j = 0; j < 4; j++) {
        int col = n0 + wx*64 + j*16 + m16;
        float bj = bias[col];
#pragma unroll
        for (int i = 0; i < 4; i++) {
            int rbase = row0 + wy*64 + i*16 + quad*4;
#pragma unroll
            for (int r = 0; r < 4; r++) {
                float v = acc[i][j][r] + bj;
                size_t idx = (size_t)(rbase + r)*N + col;
                if (EPI == 0) {
                    ((unsigned short*)Cout)[idx] = f2b(v);
                } else {
                    float gv = 0.5f * v * (1.0f + erff(v * 0.70710678118654752f));
                    ((unsigned short*)Cout)[idx] = f2b(gv);
                }
            }
        }
    }
}

// ---------------------------------------------------------------------------
// QKV GEMM: epilogue scatters directly into Qp/Kp/Vt layouts.
// Qp,Kp: [bh][SEQ][64]; Vt: [bh][64 d][SEQ] (V transposed for 32x32 PV).
// Q region pre-scaled by QSCALE. Region (Q/K/V) is uniform per block.
// ---------------------------------------------------------------------------
__global__ __launch_bounds__(256) void gemm_qkv(
    const unsigned short* __restrict__ A, const unsigned short* __restrict__ BT,
    const float* __restrict__ bias,
    unsigned short* __restrict__ Qp, unsigned short* __restrict__ Kp,
    unsigned short* __restrict__ Vp)
{
    const int K = 512;
    __shared__ __align__(16) unsigned short As[128*32];
    __shared__ __align__(16) unsigned short Bs[128*32];
    const int tid  = threadIdx.x;
    const int wave = tid >> 6, lane = tid & 63;
    const int wy = wave >> 1, wx = wave & 1;
    const int quad = lane >> 4, m16 = lane & 15;
    const int row0 = blockIdx.y * 128, n0 = blockIdx.x * 128;
    const int rdoff = (quad ^ ((m16 >> 1) & 3)) * 8;
    const int region = n0 >> 9;   // 0=Q, 1=K, 2=V (uniform per block)

    f32x4 acc[4][4];
#pragma unroll
    for (int i = 0; i < 4; i++)
#pragma unroll
        for (int j = 0; j < 4; j++) acc[i][j] = (f32x4){0.f,0.f,0.f,0.f};

    for (int kt = 0; kt < 16; ++kt) {
        const int k0 = kt << 5;
#pragma unroll
        for (int it = 0; it < 2; ++it) {
            int g  = it*256 + tid;
            int r  = g >> 2;
            int c8 = (((g & 3) ^ ((g >> 3) & 3)) << 3);
            gl2lds16(A  + (size_t)(row0 + r)*K + k0 + c8, &As[(size_t)(it*256 + wave*64)*8]);
            gl2lds16(BT + (size_t)(n0  + r)*K + k0 + c8, &Bs[(size_t)(it*256 + wave*64)*8]);
        }
        __syncthreads();
        short8 a[4], b[4];
#pragma unroll
        for (int i = 0; i < 4; i++) a[i] = *(const short8*)&As[(wy*64 + i*16 + m16)*32 + rdoff];
#pragma unroll
        for (int j = 0; j < 4; j++) b[j] = *(const short8*)&Bs[(wx*64 + j*16 + m16)*32 + rdoff];
#pragma unroll
        for (int i = 0; i < 4; i++)
#pragma unroll
            for (int j = 0; j < 4; j++)
                acc[i][j] = __builtin_amdgcn_mfma_f32_16x16x32_bf16(a[i], b[j], acc[i][j], 0, 0, 0);
        __syncthreads();
    }

    const float sc = (region == 0) ? QSCALE : 1.0f;
#pragma unroll
    for (int j = 0; j < 4; j++) {
        int col = n0 + wx*64 + j*16 + m16;
        float bj = bias[col];
        int cc = col & 511, h = cc >> 6, d = cc & 63;
#pragma unroll
        for (int i = 0; i < 4; i++) {
            int rbase = row0 + wy*64 + i*16 + quad*4;
#pragma unroll
            for (int r = 0; r < 4; r++) {
                float v = (acc[i][j][r] + bj) * sc;
                int row = rbase + r;
                int b = row >> 12, l = row & 4095;
                size_t bh = (size_t)(b*8 + h);
                if (region == 0) {
                    Qp[(bh*SEQ + l)*64 + d] = f2b(v);
                } else if (region == 1) {
                    Kp[(bh*SEQ + l)*64 + d] = f2b(v);
                } else {
                    // V transposed: Vt[bh][d][l]
                    Vp[(bh*64 + d)*SEQ + l] = f2b(v);
                }
            }
        }
    }
}

// ---------------------------------------------------------------------------
// GEMM 64x128 tile (N=512 matmuls: grid 512 blocks). bf16 out.
// ---------------------------------------------------------------------------
__global__ __launch_bounds__(256) void gemm_bt64(
    const unsigned short* __restrict__ A, const unsigned short* __restrict__ BT,
    const float* __restrict__ bias, unsigned short* __restrict__ Cout,
    int M, int N, int K)
{
    __shared__ __align__(16) unsigned short As[64*32];
    __shared__ __align__(16) unsigned short Bs[128*32];
    const int tid  = threadIdx.x;
    const int wave = tid >> 6, lane = tid & 63;
    const int wy = wave >> 1, wx = wave & 1;
    const int quad = lane >> 4, m16 = lane & 15;
    const int row0 = blockIdx.y * 64, n0 = blockIdx.x * 128;
    const int rdoff = (quad ^ ((m16 >> 1) & 3)) * 8;

    f32x4 acc[2][4];
#pragma unroll
    for (int i = 0; i < 2; i++)
#pragma unroll
        for (int j = 0; j < 4; j++) acc[i][j] = (f32x4){0.f,0.f,0.f,0.f};

    const int kIters = K >> 5;
    for (int kt = 0; kt < kIters; ++kt) {
        const int k0 = kt << 5;
        {
            int r = tid >> 2;
            int c8 = (((tid & 3) ^ ((tid >> 3) & 3)) << 3);
            gl2lds16(A + (size_t)(row0 + r)*K + k0 + c8, &As[(size_t)(wave*64)*8]);
        }
#pragma unroll
        for (int it = 0; it < 2; ++it) {
            int g  = it*256 + tid;
            int r  = g >> 2;
            int c8 = (((g & 3) ^ ((g >> 3) & 3)) << 3);
            gl2lds16(BT + (size_t)(n0 + r)*K + k0 + c8, &Bs[(size_t)(it*256 + wave*64)*8]);
        }
        __syncthreads();
        short8 a[2], b[4];
#pragma unroll
        for (int i = 0; i < 2; i++) a[i] = *(const short8*)&As[(wy*32 + i*16 + m16)*32 + rdoff];
#pragma unroll
        for (int j = 0; j < 4; j++) b[j] = *(const short8*)&Bs[(wx*64 + j*16 + m16)*32 + rdoff];
#pragma unroll
        for (int i = 0; i < 2; i++)
#pragma unroll
            for (int j = 0; j < 4; j++)
                acc[i][j] = __builtin_amdgcn_mfma_f32_16x16x32_bf16(a[i], b[j], acc[i][j], 0, 0, 0);
        __syncthreads();
    }

#pragma unroll
    for (int j = 0; j < 4; j++) {
        int col = n0 + wx*64 + j*16 + m16;
        float bj = bias[col];
#pragma unroll
        for (int i = 0; i < 2; i++) {
            int rbase = row0 + wy*32 + i*16 + quad*4;
#pragma unroll
            for (int r = 0; r < 4; r++) {
                float v = acc[i][j][r] + bj;
                Cout[(size_t)(rbase + r)*N + col] = f2b(v);
            }
        }
    }
}

// ---------------------------------------------------------------------------
// prep: all 6 weight transposes + bias concat + mask flags + kmax zero in ONE
// kernel. Blocks 0..3071 = 32x32 transpose tiles; block 3072 = misc.
// ---------------------------------------------------------------------------
__global__ __launch_bounds__(256) void prep(
    const float* __restrict__ Wq, const float* __restrict__ Wk,
    const float* __restrict__ Wv, const float* __restrict__ Wo,
    const float* __restrict__ W1, const float* __restrict__ W2,
    const float* __restrict__ bq, const float* __restrict__ bk,
    const float* __restrict__ bv, const int* __restrict__ mask,
    unsigned short* __restrict__ WqkvT, unsigned short* __restrict__ WoT,
    unsigned short* __restrict__ W1T, unsigned short* __restrict__ W2T,
    float* __restrict__ bqkv, int* __restrict__ mflag, unsigned* __restrict__ kmax2)
{
    const int id = blockIdx.x, t = threadIdx.x;
    if (id == 3072) {
        if (t < 64) {   // mask flags (64 key-tiles of 128)
            const int* m = mask + t*128;
            int all = 1;
            for (int i = 0; i < 128; i += 4) {
                int4 v = *(const int4*)(m + i);
                all &= (v.x && v.y && v.z && v.w) ? 1 : 0;
            }
            mflag[t] = all;
        }
        if (t < 16) kmax2[t] = 0u;
        for (int i = t; i < 1536; i += 256)
            bqkv[i] = (i < 512) ? bq[i] : ((i < 1024) ? bk[i-512] : bv[i-1024]);
        return;
    }
    __shared__ float tt[32][33];
    const float* W; unsigned short* WT; int K, N, bx, by;
    if (id < 256)       { W = Wq; WT = WqkvT;            K = 512;  N = 512;  bx = id & 15;  by = id >> 4; }
    else if (id < 512)  { int l = id - 256;  W = Wk; WT = WqkvT + 512*512;  K = 512;  N = 512;  bx = l & 15; by = l >> 4; }
    else if (id < 768)  { int l = id - 512;  W = Wv; WT = WqkvT + 1024*512; K = 512;  N = 512;  bx = l & 15; by = l >> 4; }
    else if (id < 1024) { int l = id - 768;  W = Wo; WT = WoT;              K = 512;  N = 512;  bx = l & 15; by = l >> 4; }
    else if (id < 2048) { int l = id - 1024; W = W1; WT = W1T;              K = 512;  N = 2048; bx = l & 63; by = l >> 6; }
    else                { int l = id - 2048; W = W2; WT = W2T;              K = 2048; N = 512;  bx = l & 15; by = l >> 4; }
    const int n0 = bx*32, k0 = by*32;
    const int x = t & 31, y = t >> 5;
#pragma unroll
    for (int yy = y; yy < 32; yy += 8) tt[yy][x] = W[(size_t)(k0+yy)*N + n0 + x];
    __syncthreads();
#pragma unroll
    for (int yy = y; yy < 32; yy += 8) WT[(size_t)(n0+yy)*K + k0 + x] = f2b(tt[x][yy]);
}

// kmax2[bh] = max_row ||K_row||^2, via atomicMax on positive-float bits.
__global__ __launch_bounds__(256) void kmax_k(
    const unsigned short* __restrict__ Kp, unsigned* __restrict__ kmax2)
{
    const int bh = blockIdx.x, t = threadIdx.x;
    const int row = blockIdx.y*256 + t;
    const unsigned short* kp = Kp + ((size_t)bh*SEQ + row)*64;
    float s = 0.f;
#pragma unroll
    for (int c = 0; c < 8; ++c) {
        short8 v = *(const short8*)(kp + c*8);
#pragma unroll
        for (int j = 0; j < 8; ++j) { float f = b2f(v[j]); s += f*f; }
    }
#pragma unroll
    for (int off = 32; off >= 1; off >>= 1)
        s = fmaxf(s, __shfl_xor(s, off, 64));
    if ((t & 63) == 0) atomicMax(&kmax2[bh], __float_as_uint(s));
}

// ---------------------------------------------------------------------------
// Flash attention, 32x32x16 MFMA, fixed-bound softmax, key-split wave pairs.
// grid (SEQ/256, B*H), 512 threads = 8 waves. Wave = (qsub = wave&3,
// parity = wave>>2). Each qsub owns 64 q rows; parity 0 processes keys 0-63
// of each 128-key tile (kg 0,1), parity 1 keys 64-127 (kg 2,3). Fixed-bound
// softmax (same M for both parities) makes partial (accO, rs) additive: at
// the end parity-1 dumps partials into the dead K/V LDS buffers and parity-0
// merges + stores. 2048 total waves = 2 waves/SIMD (vs 1 for the 64q/wave
// non-split layout) -> latency hiding restored.
// K tile [128][64] and V^T tile [64][128] double-buffered (64 KB LDS),
// XOR-swizzled; one barrier per tile (stage-next || compute).
// QK^T acc preloaded with -M so p = exp2(acc) directly. P -> bf16 B-operand
// via cvt_pk + permlane32_swap; PV on the same full-rate 32x32x16 MFMA.
// ---------------------------------------------------------------------------
__global__ __launch_bounds__(512, 2) void flash_attn(
    const unsigned short* __restrict__ Qp, const unsigned short* __restrict__ Kp,
    const unsigned short* __restrict__ Vt, const int* __restrict__ mask,
    const int* __restrict__ flags, const unsigned* __restrict__ kmax2,
    unsigned short* __restrict__ O)
{
    __shared__ __align__(16) unsigned short Ks[2][128*64];   // [buf][key][d]
    __shared__ __align__(16) unsigned short Vs[2][64*128];   // [buf][d][key]
    __shared__ float rsh[4][2][64];                          // rs partials
    const int tid = threadIdx.x, wave = tid >> 6, lane = tid & 63;
    const int qsub = wave & 3, parity = wave >> 2;
    const int c = lane & 31, l5 = lane >> 5;
    const int bh = blockIdx.y, b = bh >> 3, h = bh & 7;
    const int qbase = blockIdx.x * 256 + qsub * 64;

    const unsigned short* Qb = Qp + (size_t)bh*SEQ*64;
    const unsigned short* Kb = Kp + (size_t)bh*SEQ*64;
    const unsigned short* Vb = Vt + (size_t)bh*64*SEQ;
    const int* mbase = mask + b*SEQ;
    const int* fbase = flags + b*(SEQ/128);
    const float kmx = __uint_as_float(kmax2[bh]);

    // Q fragments: qf[qs][t] = Q[qbase+qs*32+c][t*16 + l5*8 .. +7]  (B-operand)
    short8 qf[2][4];
    float Mq[2];
#pragma unroll
    for (int qs = 0; qs < 2; ++qs) {
        const unsigned short* qp = Qb + (size_t)(qbase + qs*32 + c)*64 + l5*8;
        float qn2 = 0.f;
#pragma unroll
        for (int t = 0; t < 4; ++t) {
            qf[qs][t] = *(const short8*)(qp + t*16);
#pragma unroll
            for (int j = 0; j < 8; ++j) { float f = b2f(qf[qs][t][j]); qn2 += f*f; }
        }
        qn2 += __shfl_xor(qn2, 32, 64);      // halves hold complementary d
        Mq[qs] = sqrtf(qn2 * kmx);
    }

    f32x16 accO[2][2];                        // [qs][dgrp]: O^T[d][q] partial
#pragma unroll
    for (int qs = 0; qs < 2; ++qs)
#pragma unroll
        for (int dg = 0; dg < 2; ++dg)
#pragma unroll
            for (int r = 0; r < 16; ++r) accO[qs][dg][r] = 0.f;
    float rs0 = 0.f, rs1 = 0.f;

    // stage K[128][64] (8 chunks/row, swz ^row&7) and V^T[64][128]
    // (16 chunks/row, swz ^row&15) into buffer nb for key-tile ktn.
    // 512 threads: 2 iters each for K (1024 chunks) and V (1024 chunks).
#define STAGE(nb, ktn) do {                                                   \
        const int key0s = (ktn)*128;                                          \
        _Pragma("unroll")                                                     \
        for (int it = 0; it < 2; ++it) {                                      \
            int idx = it*512 + tid;                                           \
            int r = idx >> 3, chn = idx & 7;                                  \
            gl2lds16(Kb + (size_t)(key0s + r)*64 + ((chn ^ (r & 7)) << 3),    \
                     &Ks[nb][(it*512 + wave*64)*8]);                          \
        }                                                                     \
        _Pragma("unroll")                                                     \
        for (int it = 0; it < 2; ++it) {                                      \
            int idx = it*512 + tid;                                           \
            int r = idx >> 4, chn = idx & 15;                                 \
            gl2lds16(Vb + (size_t)r*SEQ + key0s + ((chn ^ (r & 15)) << 3),    \
                     &Vs[nb][(it*512 + wave*64)*8]);                          \
        }                                                                     \
    } while (0)

    STAGE(0, 0);
    __syncthreads();                          // implicit vmcnt(0) drain
    int cb = 0;
    const int NT = SEQ/128;

    for (int kt = 0; kt < NT; ++kt) {
        if (kt + 1 < NT) STAGE(cb ^ 1, kt + 1);   // prefetch next tile
        const int allones = fbase[kt];
        const int key0 = kt * 128;
        const unsigned short* Kt  = Ks[cb];
        const unsigned short* Vtl = Vs[cb];

#pragma unroll
        for (int g = 0; g < 2; ++g) {
            const int kg = parity*2 + g;       // this wave's 32-key group
            // ---- QK^T: A = K rows (32 keys), B = Q^T. acc preloaded -M.
            short8 kf[4];
#pragma unroll
            for (int t = 0; t < 4; ++t) {
                int row = kg*32 + c;
                int chn = (t*2 + l5) ^ (row & 7);
                kf[t] = *(const short8*)&Kt[row*64 + chn*8];
            }
            f32x16 s0, s1;
#pragma unroll
            for (int r = 0; r < 16; ++r) { s0[r] = -Mq[0]; s1[r] = -Mq[1]; }
#pragma unroll
            for (int t = 0; t < 4; ++t) {
                s0 = __builtin_amdgcn_mfma_f32_32x32x16_bf16(kf[t], qf[0][t], s0, 0, 0, 0);
                s1 = __builtin_amdgcn_mfma_f32_32x32x16_bf16(kf[t], qf[1][t], s1, 0, 0, 0);
            }
            if (!allones) {
#pragma unroll
                for (int r = 0; r < 16; ++r) {
                    int mv = mbase[key0 + kg*32 + (r & 3) + 8*(r >> 2) + 4*l5];
                    if (!mv) { s0[r] = -1e9f; s1[r] = -1e9f; }
                }
            }
            // ---- softmax numerators (keys for this lane: (r&3)+8*(r>>2)+4*l5)
            float pa[16], pc[16];
#pragma unroll
            for (int r = 0; r < 16; ++r) { pa[r] = EXP2(s0[r]); pc[r] = EXP2(s1[r]); }
            rs0 += (((pa[0]+pa[1])+(pa[2]+pa[3])) + ((pa[4]+pa[5])+(pa[6]+pa[7])))
                 + (((pa[8]+pa[9])+(pa[10]+pa[11])) + ((pa[12]+pa[13])+(pa[14]+pa[15])));
            rs1 += (((pc[0]+pc[1])+(pc[2]+pc[3])) + ((pc[4]+pc[5])+(pc[6]+pc[7])))
                 + (((pc[8]+pc[9])+(pc[10]+pc[11])) + ((pc[12]+pc[13])+(pc[14]+pc[15])));

            // ---- PV: A = V^T rows (32 d), B = P^T via cvt_pk + permlane32_swap
            short8 vf[2][2];   // [kchunk16][dgrp]
#pragma unroll
            for (int c2 = 0; c2 < 2; ++c2)
#pragma unroll
                for (int dg = 0; dg < 2; ++dg) {
                    int row = dg*32 + c;
                    int chn = ((kg*2 + c2)*2 + l5) ^ (row & 15);
                    vf[c2][dg] = *(const short8*)&Vtl[row*128 + chn*8];
                }
#pragma unroll
            for (int c2 = 0; c2 < 2; ++c2) {
                short8 pf0 = pfrag8(&pa[c2*8]);
                short8 pf1 = pfrag8(&pc[c2*8]);
                accO[0][0] = __builtin_amdgcn_mfma_f32_32x32x16_bf16(vf[c2][0], pf0, accO[0][0], 0, 0, 0);
                accO[0][1] = __builtin_amdgcn_mfma_f32_32x32x16_bf16(vf[c2][1], pf0, accO[0][1], 0, 0, 0);
                accO[1][0] = __builtin_amdgcn_mfma_f32_32x32x16_bf16(vf[c2][0], pf1, accO[1][0], 0, 0, 0);
                accO[1][1] = __builtin_amdgcn_mfma_f32_32x32x16_bf16(vf[c2][1], pf1, accO[1][1], 0, 0, 0);
            }
        }
        __syncthreads();      // drains prefetch vmcnt + protects buffer swap
        cb ^= 1;
    }
#undef STAGE

    // ---- cross-parity merge: partials are additive (same fixed bound M).
    // Merge area: dead K/V buffers. qsub 0,1 -> Ks (2x16KB); 2,3 -> Vs.
    float* mp = (qsub < 2) ? ((float*)&Ks[0][0] + qsub*4096)
                           : ((float*)&Vs[0][0] + (qsub - 2)*4096);
    if (parity) {
#pragma unroll
        for (int qs = 0; qs < 2; ++qs)
#pragma unroll
            for (int dg = 0; dg < 2; ++dg)
#pragma unroll
                for (int r = 0; r < 16; ++r)
                    mp[(qs*2 + dg)*1024 + r*64 + lane] = accO[qs][dg][r];
        rsh[qsub][0][lane] = rs0;
        rsh[qsub][1][lane] = rs1;
    }
    __syncthreads();
    if (!parity) {
#pragma unroll
        for (int qs = 0; qs < 2; ++qs)
#pragma unroll
            for (int dg = 0; dg < 2; ++dg)
#pragma unroll
                for (int r = 0; r < 16; ++r)
                    accO[qs][dg][r] += mp[(qs*2 + dg)*1024 + r*64 + lane];
        rs0 += rsh[qsub][0][lane];
        rs1 += rsh[qsub][1][lane];

        // final l reduction (keys split across lane halves)
        rs0 += __shfl_xor(rs0, 32, 64);
        rs1 += __shfl_xor(rs1, 32, 64);
        float rl[2] = { 1.0f/rs0, 1.0f/rs1 };
#pragma unroll
        for (int qs = 0; qs < 2; ++qs) {
            int qrow = qbase + qs*32 + c;
            unsigned short* op = O + (size_t)(b*SEQ + qrow)*D_EMBED + h*HEAD_DIM;
#pragma unroll
            for (int dg = 0; dg < 2; ++dg)
#pragma unroll
                for (int q4 = 0; q4 < 4; ++q4) {
                    short4_t o = pk4(accO[qs][dg][q4*4+0]*rl[qs], accO[qs][dg][q4*4+1]*rl[qs],
                                     accO[qs][dg][q4*4+2]*rl[qs], accO[qs][dg][q4*4+3]*rl[qs]);
                    *(short4_t*)&op[dg*32 + q4*8 + l5*4] = o;
                }
        }
    }
}

// ---------------------------------------------------------------------------
// ln1: y = LayerNorm(x_f32 + attn_bf16)*g + be -> bf16 only
// ---------------------------------------------------------------------------
__global__ __launch_bounds__(256) void ln_res1(
    const float* __restrict__ A, const unsigned short* __restrict__ Bv,
    const float* __restrict__ g, const float* __restrict__ be,
    unsigned short* __restrict__ Yb)
{
    const int wave = threadIdx.x >> 6, lane = threadIdx.x & 63;
    const int row = blockIdx.x * 4 + wave;
    const float* ap = A + (size_t)row*512 + lane*8;
    short8 bv = *(const short8*)(Bv + (size_t)row*512 + lane*8);
    float v[8]; float s = 0.f;
#pragma unroll
    for (int j = 0; j < 8; j++) { v[j] = ap[j] + b2f(bv[j]); s += v[j]; }
#pragma unroll
    for (int off = 32; off >= 1; off >>= 1) s += __shfl_xor(s, off, 64);
    float mu = s * (1.f/512.f);
    float q = 0.f;
#pragma unroll
    for (int j = 0; j < 8; j++) { v[j] -= mu; q += v[j]*v[j]; }
#pragma unroll
    for (int off = 32; off >= 1; off >>= 1) q += __shfl_xor(q, off, 64);
    float rstd = rsqrtf(q * (1.f/512.f) + 1e-5f);
#pragma unroll
    for (int j = 0; j < 8; j++) {
        float y = v[j]*rstd*g[lane*8+j] + be[lane*8+j];
        Yb[(size_t)row*512 + lane*8 + j] = f2b(y);
    }
}

// ---------------------------------------------------------------------------
// ln2: y = LayerNorm(h_bf16 + ff_bf16)*g + be -> fp32 out
// ---------------------------------------------------------------------------
__global__ __launch_bounds__(256) void ln_res2(
    const unsigned short* __restrict__ A, const unsigned short* __restrict__ Bv,
    const float* __restrict__ g, const float* __restrict__ be,
    float* __restrict__ Yf)
{
    const int wave = threadIdx.x >> 6, lane = threadIdx.x & 63;
    const int row = blockIdx.x * 4 + wave;
    short8 av = *(const short8*)(A  + (size_t)row*512 + lane*8);
    short8 bv = *(const short8*)(Bv + (size_t)row*512 + lane*8);
    float v[8]; float s = 0.f;
#pragma unroll
    for (int j = 0; j < 8; j++) { v[j] = b2f(av[j]) + b2f(bv[j]); s += v[j]; }
#pragma unroll
    for (int off = 32; off >= 1; off >>= 1) s += __shfl_xor(s, off, 64);
    float mu = s * (1.f/512.f);
    float q = 0.f;
#pragma unroll
    for (int j = 0; j < 8; j++) { v[j] -= mu; q += v[j]*v[j]; }
#pragma unroll
    for (int off = 32; off >= 1; off >>= 1) q += __shfl_xor(q, off, 64);
    float rstd = rsqrtf(q * (1.f/512.f) + 1e-5f);
#pragma unroll
    for (int j = 0; j < 8; j++) {
        float y = v[j]*rstd*g[lane*8+j] + be[lane*8+j];
        Yf[(size_t)row*512 + lane*8 + j] = y;
    }
}

__global__ __launch_bounds__(256) void cvt_f32_bf16(
    const float* __restrict__ X, unsigned short* __restrict__ Y, int n)
{
    int idx = (blockIdx.x * 256 + threadIdx.x) * 4;
    if (idx < n) {
        float4 v = *(const float4*)(X + idx);
        Y[idx+0] = f2b(v.x); Y[idx+1] = f2b(v.y);
        Y[idx+2] = f2b(v.z); Y[idx+3] = f2b(v.w);
    }
}

extern "C" void kernel_launch(void* const* d_in, const int* in_sizes, int n_in,
                              void* d_out, int out_size, void* d_ws, size_t ws_size,
                              hipStream_t stream)
{
    const float* x    = (const float*)d_in[0];
    const int*   mask = (const int*)  d_in[1];
    const float* Wq = (const float*)d_in[2];  const float* bq = (const float*)d_in[3];
    const float* Wk = (const float*)d_in[4];  const float* bk = (const float*)d_in[5];
    const float* Wv = (const float*)d_in[6];  const float* bv = (const float*)d_in[7];
    const float* Wo = (const float*)d_in[8];  const float* bo = (const float*)d_in[9];
    const float* ln1g = (const float*)d_in[10]; const float* ln1b = (const float*)d_in[11];
    const float* ln2g = (const float*)d_in[12]; const float* ln2b = (const float*)d_in[13];
    const float* W1 = (const float*)d_in[14]; const float* b1 = (const float*)d_in[15];
    const float* W2 = (const float*)d_in[16]; const float* b2 = (const float*)d_in[17];
    float* out = (float*)d_out;

    char* ws = (char*)d_ws;
    const size_t MB = 1024*1024;
    // liveness-planned map (peak 55 MB):
    unsigned short* xb    = (unsigned short*)(ws + 0);           // 0..8, dead after QKV GEMM
    unsigned short* WqkvT = (unsigned short*)(ws + 8*MB);        // 8..9.5
    unsigned short* W1T   = (unsigned short*)(ws + 10*MB);       // 10..12
    unsigned short* W2T   = (unsigned short*)(ws + 12*MB);       // 12..14
    unsigned short* WoT   = (unsigned short*)(ws + 14*MB);       // 14..14.5
    float*          bqkv  = (float*)(ws + 14*MB + 512*1024);     // 6 KB
    int*            mflag = (int*)(ws + 14*MB + 768*1024);       // 256 B
    unsigned*       kmaxb = (unsigned*)(ws + 14*MB + 772*1024);  // 64 B
    unsigned short* Qp    = (unsigned short*)(ws + 15*MB);       // 15..23, dead after flash
    unsigned short* Kp    = (unsigned short*)(ws + 23*MB);       // 23..31, dead after flash
    unsigned short* Vp    = (unsigned short*)(ws + 31*MB);       // 31..39 (V^T), dead after flash
    unsigned short* ctx   = (unsigned short*)(ws + 39*MB);       // 39..47, dead after Wo GEMM
    unsigned short* atfb  = (unsigned short*)(ws + 47*MB);       // 47..55, dead after ln1
    unsigned short* hb    = (unsigned short*)(ws + 0);           // 0..8, overlays dead xb
    unsigned short* Gb    = (unsigned short*)(ws + 15*MB);       // 15..47, overlays Qp/Kp/Vp/ctx
    unsigned short* ffb   = (unsigned short*)(ws + 47*MB);       // 47..55, overlays dead atfb

    cvt_f32_bf16<<<4096, 256, 0, stream>>>(x, xb, M_ROWS*D_EMBED);
    prep<<<3073, 256, 0, stream>>>(Wq, Wk, Wv, Wo, W1, W2, bq, bk, bv, mask,
                                   WqkvT, WoT, W1T, W2T, bqkv, mflag, kmaxb);

    // fused QKV projection -> direct Qp/Kp/Vt layouts (Q pre-scaled by QSCALE)
    gemm_qkv<<<dim3(12,64), 256, 0, stream>>>(xb, WqkvT, bqkv, Qp, Kp, Vp);

    kmax_k<<<dim3(16,16), 256, 0, stream>>>(Kp, kmaxb);
    flash_attn<<<dim3(SEQ/256, 16), 512, 0, stream>>>(Qp, Kp, Vp, mask, mflag, kmaxb, ctx);

    gemm_bt64<<<dim3(4,128), 256, 0, stream>>>(ctx, WoT, bo, atfb, M_ROWS, 512, 512);
    ln_res1<<<M_ROWS/4, 256, 0, stream>>>(x, atfb, ln1g, ln1b, hb);

    gemm_bt<2><<<dim3(16,64), 256, 0, stream>>>(hb, W1T, b1, Gb, M_ROWS, D_FF, 512);
    gemm_bt64<<<dim3(4,128), 256, 0, stream>>>(Gb, W2T, b2, ffb, M_ROWS, 512, D_FF);
    ln_res2<<<M_ROWS/4, 256, 0, stream>>>(hb, ffb, ln2g, ln2b, out);
}